// Round 1
// baseline (10054.039 us; speedup 1.0000x reference)
//
#include <hip/hip_runtime.h>

#define TT 512
#define NN 64
#define DD 1024
#define HH 1024
#define NWG 256
#define NTHR 256

typedef __attribute__((ext_vector_type(8))) short bf16x8;
typedef __attribute__((ext_vector_type(4))) float f32x4;
typedef __attribute__((ext_vector_type(8))) unsigned short u16x8;

// Packed/tiled bf16 operands (static device memory; rewritten every launch).
// Layout: vec8 index o8 = (colgrp*32 + kk)*64 + lane, element e:
//   matrix[col = colgrp*16 + (lane&15)][k = kk*32 + (lane>>4)*8 + e]
__device__ unsigned short g_wih[192 * 32 * 64 * 8];
__device__ unsigned short g_whh[192 * 32 * 64 * 8];
// x tiles: o8 = ((t*4 + eg)*32 + kk)*64 + lane; env = eg*16 + (lane&15)
__device__ unsigned short g_x[(size_t)TT * 4 * 32 * 64 * 8];
__device__ unsigned g_bar;

__device__ __forceinline__ unsigned short f2bf(float f) {
  unsigned u = __float_as_uint(f);
  u += 0x7fffu + ((u >> 16) & 1u);   // round-to-nearest-even
  return (unsigned short)(u >> 16);
}

__global__ void prep_kernel(const float* __restrict__ x,
                            const float* __restrict__ wih,
                            const float* __restrict__ whh) {
  if (blockIdx.x == 0 && threadIdx.x == 0) g_bar = 0u;
  const int W8 = 3072 * 128;          // 393216 vec8 groups per weight matrix
  const int X8 = TT * NN * 128;       // 4194304 vec8 groups for x
  const int gsz = gridDim.x * blockDim.x;
  for (int idx = blockIdx.x * blockDim.x + threadIdx.x; idx < 2 * W8 + X8; idx += gsz) {
    if (idx < 2 * W8) {
      const float* src = (idx < W8) ? wih : whh;
      unsigned short* dst = (idx < W8) ? g_wih : g_whh;
      int i8 = (idx < W8) ? idx : idx - W8;
      size_t g = (size_t)i8 * 8;            // coalesced read offset
      int col = (int)(g >> 10);
      int k = (int)(g & 1023);
      int kk = k >> 5, lg = (k >> 3) & 3;
      int cg = col >> 4;
      int l = (col & 15) | (lg << 4);
      size_t o8 = ((size_t)cg * 32 + kk) * 64 + l;
      const float* p = src + g;
      float4 v0 = *(const float4*)(p);
      float4 v1 = *(const float4*)(p + 4);
      u16x8 u;
      u[0] = f2bf(v0.x); u[1] = f2bf(v0.y); u[2] = f2bf(v0.z); u[3] = f2bf(v0.w);
      u[4] = f2bf(v1.x); u[5] = f2bf(v1.y); u[6] = f2bf(v1.z); u[7] = f2bf(v1.w);
      *(u16x8*)(dst + o8 * 8) = u;
    } else {
      int i8 = idx - 2 * W8;
      size_t g = (size_t)i8 * 8;
      int row = (int)(g >> 10);             // t*64 + env
      int k = (int)(g & 1023);
      int t = row >> 6, env = row & 63;
      int eg = env >> 4;
      int kk = k >> 5, lg = (k >> 3) & 3;
      int l = (env & 15) | (lg << 4);
      size_t o8 = (((size_t)t * 4 + eg) * 32 + kk) * 64 + l;
      const float* p = x + g;
      float4 v0 = *(const float4*)(p);
      float4 v1 = *(const float4*)(p + 4);
      u16x8 u;
      u[0] = f2bf(v0.x); u[1] = f2bf(v0.y); u[2] = f2bf(v0.z); u[3] = f2bf(v0.w);
      u[4] = f2bf(v1.x); u[5] = f2bf(v1.y); u[6] = f2bf(v1.z); u[7] = f2bf(v1.w);
      *(u16x8*)(g_x + o8 * 8) = u;
    }
  }
}

__global__ __launch_bounds__(NTHR) void scan_kernel(const float* __restrict__ hx,
                                                    const float* __restrict__ mask,
                                                    const float* __restrict__ bih,
                                                    const float* __restrict__ bhh,
                                                    float* __restrict__ out) {
  __shared__ u16x8 hAv[2048];        // masked h, tiled [kk][lane][8] = 32KB
  __shared__ float ghC[4][16][16];   // gate tiles: r, z, i_n, h_n
  __shared__ float hmf[16][16];      // masked h (fp32) for this wg's j-window

  const int tid = threadIdx.x;
  const int bid = blockIdx.x;
  // XCD-swizzle: wgs sharing a j-group land on the same XCD (perf-only)
  const int jg = (bid & 7) * 8 + ((bid >> 3) & 7);   // 0..63
  const int eg = bid >> 6;                            // 0..3
  const int j0 = jg * 16;
  const int e0 = eg * 16;
  const int w = tid >> 6;    // wave 0..3 -> gate tile r, z, i_n, h_n
  const int l = tid & 63;

  const int cl = tid & 63;
  const int se = cl & 15;             // staged env (local)
  const int ko = (cl >> 4) << 3;      // k sub-offset within 32-k block
  const float me_base_env = 0.f; (void)me_base_env;

  for (int t = 0; t < TT; ++t) {
    const float* hprev = (t == 0) ? hx : (out + (size_t)(t - 1) * NN * HH);

    // ---- stage masked h_{t-1} into LDS, tiled fragment order ----
    {
      float m = mask[t * NN + e0 + se];
      const float* hrow = hprev + (size_t)(e0 + se) * HH + ko;
      #pragma unroll
      for (int it = 0; it < 8; ++it) {
        int kk = (tid >> 6) + it * 4;       // 0..31
        int k = kk * 32 + ko;
        float4 v0 = *(const float4*)(hrow + kk * 32);
        float4 v1 = *(const float4*)(hrow + kk * 32 + 4);
        float f0 = v0.x * m, f1 = v0.y * m, f2 = v0.z * m, f3 = v0.w * m;
        float f4 = v1.x * m, f5 = v1.y * m, f6 = v1.z * m, f7 = v1.w * m;
        u16x8 u;
        u[0] = f2bf(f0); u[1] = f2bf(f1); u[2] = f2bf(f2); u[3] = f2bf(f3);
        u[4] = f2bf(f4); u[5] = f2bf(f5); u[6] = f2bf(f6); u[7] = f2bf(f7);
        hAv[kk * 64 + cl] = u;
        unsigned d = (unsigned)(k - j0);
        if (d < 16u) {
          hmf[se][d + 0] = f0; hmf[se][d + 1] = f1;
          hmf[se][d + 2] = f2; hmf[se][d + 3] = f3;
          hmf[se][d + 4] = f4; hmf[se][d + 5] = f5;
          hmf[se][d + 6] = f6; hmf[se][d + 7] = f7;
        }
      }
    }
    __syncthreads();

    // ---- MFMA: each wave computes one 16x16 gate tile ----
    f32x4 acc = {0.f, 0.f, 0.f, 0.f};
    if (w != 2) {   // h-contribution: r(w0), z(w1), h_n(w3)
      int cg = jg + (w == 1 ? 64 : (w == 3 ? 128 : 0));
      const bf16x8* bp = (const bf16x8*)g_whh + (size_t)cg * 2048;
      const bf16x8* ap = (const bf16x8*)hAv;
      #pragma unroll 8
      for (int kk = 0; kk < 32; ++kk)
        acc = __builtin_amdgcn_mfma_f32_16x16x32_bf16(ap[kk * 64 + l], bp[kk * 64 + l], acc, 0, 0, 0);
    }
    if (w != 3) {   // x-contribution: r(w0), z(w1), i_n(w2)
      int cg = jg + (w == 1 ? 64 : (w == 2 ? 128 : 0));
      const bf16x8* bp = (const bf16x8*)g_wih + (size_t)cg * 2048;
      const bf16x8* ap = (const bf16x8*)g_x + ((size_t)t * 4 + eg) * 2048;
      #pragma unroll 8
      for (int kk = 0; kk < 32; ++kk)
        acc = __builtin_amdgcn_mfma_f32_16x16x32_bf16(ap[kk * 64 + l], bp[kk * 64 + l], acc, 0, 0, 0);
    }
    {
      // C/D layout (m89-verified): col = lane&15, row = (lane>>4)*4 + i
      int col = l & 15, r0 = (l >> 4) * 4;
      #pragma unroll
      for (int i = 0; i < 4; ++i) ghC[w][r0 + i][col] = acc[i];
    }
    __syncthreads();

    // ---- elementwise GRU update: 256 threads = 16 env x 16 j ----
    {
      int e = tid >> 4, jj = tid & 15;
      int j = j0 + jj;
      float Cr = ghC[0][e][jj], Cz = ghC[1][e][jj];
      float Ci = ghC[2][e][jj], Chn = ghC[3][e][jj];
      float pr = Cr + bih[j] + bhh[j];
      float pz = Cz + bih[HH + j] + bhh[HH + j];
      float r = 1.f / (1.f + __expf(-pr));
      float z = 1.f / (1.f + __expf(-pz));
      float hn = Chn + bhh[2 * HH + j];
      float gn = Ci + bih[2 * HH + j] + r * hn;
      float e2g = __expf(2.f * gn);
      float n = 1.f - 2.f / (e2g + 1.f);
      float hnew = (1.f - z) * n + z * hmf[e][jj];
      out[(size_t)t * NN * HH + (size_t)(e0 + e) * HH + j] = hnew;
      if (t == TT - 1)
        out[(size_t)TT * NN * HH + (size_t)(e0 + e) * HH + j] = hnew;
    }

    // ---- grid barrier (epoch counter, agent scope) ----
    if (t + 1 < TT) {
      __syncthreads();
      if (tid == 0) {
        __builtin_amdgcn_fence(__ATOMIC_RELEASE, "agent");
        __hip_atomic_fetch_add(&g_bar, 1u, __ATOMIC_RELAXED, __HIP_MEMORY_SCOPE_AGENT);
        unsigned tgt = (unsigned)(t + 1) * NWG;
        while (__hip_atomic_load(&g_bar, __ATOMIC_RELAXED, __HIP_MEMORY_SCOPE_AGENT) < tgt)
          __builtin_amdgcn_s_sleep(2);
        __builtin_amdgcn_fence(__ATOMIC_ACQUIRE, "agent");
      }
      __syncthreads();
    }
  }
}

extern "C" void kernel_launch(void* const* d_in, const int* in_sizes, int n_in,
                              void* d_out, int out_size, void* d_ws, size_t ws_size,
                              hipStream_t stream) {
  (void)in_sizes; (void)n_in; (void)d_ws; (void)ws_size; (void)out_size;
  const float* x    = (const float*)d_in[0];
  const float* hx   = (const float*)d_in[1];
  const float* mask = (const float*)d_in[2];
  const float* wih  = (const float*)d_in[3];
  const float* whh  = (const float*)d_in[4];
  const float* bih  = (const float*)d_in[5];
  const float* bhh  = (const float*)d_in[6];
  float* out = (float*)d_out;

  prep_kernel<<<2048, 256, 0, stream>>>(x, wih, whh);
  scan_kernel<<<NWG, NTHR, 0, stream>>>(hx, mask, bih, bhh, out);
}

// Round 2
// 3109.084 us; speedup vs baseline: 3.2338x; 3.2338x over previous
//
#include <hip/hip_runtime.h>

#define TT 512
#define NN 64
#define DD 1024
#define HH 1024

typedef __attribute__((ext_vector_type(8))) short bf16x8;
typedef __attribute__((ext_vector_type(4))) float f32x4;
typedef __attribute__((ext_vector_type(8))) unsigned short u16x8;
typedef __attribute__((ext_vector_type(4))) int i32x4;

// ---- static device buffers (rewritten every launch by prep/gemm) ----
// fragment-tiled bf16: vec8 idx = (tile*32 + kk)*64 + lane, elem e:
//   matrix[col = tile*16 + (lane&15)][k = kk*32 + (lane>>4)*8 + e]
__device__ unsigned short g_wih[192u * 2048 * 8];            // 6 MB
__device__ unsigned short g_whh[192u * 2048 * 8];            // 6 MB
__device__ unsigned short g_x[2048u * 2048 * 8];             // 67 MB, tile=(t*4+eg)
// gi (x-projection, bf16): [(t*4+eg)*64 + jg][gate][env16][jj16]
__device__ unsigned short g_gi[(size_t)2048 * 64 * 768];     // 201 MB
// h state tiles (masked, bf16): [parity][eg][2048 vec8][8]
__device__ unsigned short g_hbuf[2u * 4 * 2048 * 8];
__device__ int g_flags[256];                                 // [eg*64 + jg]

__device__ __forceinline__ unsigned short f2bf(float f) {
  unsigned u = __float_as_uint(f);
  u += 0x7fffu + ((u >> 16) & 1u);
  return (unsigned short)(u >> 16);
}

// LLC-coherent (cross-XCD) 16B load / 2B store, bypassing L1+L2
__device__ __forceinline__ i32x4 load16_sc(const void* p) {
  i32x4 v;
  asm volatile("global_load_dwordx4 %0, %1, off sc0 sc1" : "=v"(v) : "v"(p));
  return v;
}
__device__ __forceinline__ void store2_sc(void* p, unsigned short s) {
  unsigned w = s;
  asm volatile("global_store_short %0, %1, off sc0 sc1" :: "v"(p), "v"(w) : "memory");
}

__global__ void prep_kernel(const float* __restrict__ x,
                            const float* __restrict__ wih,
                            const float* __restrict__ whh) {
  if (blockIdx.x == 0 && threadIdx.x < 256) g_flags[threadIdx.x] = -1;
  const int W8 = 192 * 2048;          // vec8 groups per weight matrix
  const int X8 = 2048 * 2048;         // vec8 groups for x
  const int gsz = gridDim.x * blockDim.x;
  for (int idx = blockIdx.x * blockDim.x + threadIdx.x; idx < 2 * W8 + X8; idx += gsz) {
    if (idx < 2 * W8) {
      const float* src = (idx < W8) ? wih : whh;
      unsigned short* dst = (idx < W8) ? g_wih : g_whh;
      int i8 = (idx < W8) ? idx : idx - W8;
      size_t g = (size_t)i8 * 8;
      int col = (int)(g >> 10);
      int k = (int)(g & 1023);
      int kk = k >> 5, lg = (k >> 3) & 3;
      int cg = col >> 4;
      int l = (col & 15) | (lg << 4);
      size_t o8 = ((size_t)cg * 32 + kk) * 64 + l;
      const float* p = src + g;
      float4 v0 = *(const float4*)(p);
      float4 v1 = *(const float4*)(p + 4);
      u16x8 u;
      u[0] = f2bf(v0.x); u[1] = f2bf(v0.y); u[2] = f2bf(v0.z); u[3] = f2bf(v0.w);
      u[4] = f2bf(v1.x); u[5] = f2bf(v1.y); u[6] = f2bf(v1.z); u[7] = f2bf(v1.w);
      *(u16x8*)(dst + o8 * 8) = u;
    } else {
      int i8 = idx - 2 * W8;
      size_t g = (size_t)i8 * 8;
      int row = (int)(g >> 10);             // t*64 + env
      int k = (int)(g & 1023);
      int t = row >> 6, env = row & 63;
      int eg = env >> 4;
      int kk = k >> 5, lg = (k >> 3) & 3;
      int l = (env & 15) | (lg << 4);
      size_t o8 = (((size_t)t * 4 + eg) * 32 + kk) * 64 + l;
      const float* p = x + g;
      float4 v0 = *(const float4*)(p);
      float4 v1 = *(const float4*)(p + 4);
      u16x8 u;
      u[0] = f2bf(v0.x); u[1] = f2bf(v0.y); u[2] = f2bf(v0.z); u[3] = f2bf(v0.w);
      u[4] = f2bf(v1.x); u[5] = f2bf(v1.y); u[6] = f2bf(v1.z); u[7] = f2bf(v1.w);
      *(u16x8*)(g_x + o8 * 8) = u;
    }
  }
}

// ---- gi = x * wih^T, 128x128 tile, BK=128, reg-prefetch + LDS ----
__global__ __launch_bounds__(256) void gemm_gi() {
  extern __shared__ char smem[];
  unsigned short* As = (unsigned short*)smem;      // 8mt x 4kk x 64 x 8 = 32KB
  unsigned short* Bs = As + 2048 * 8;              // 32KB
  const int tid = threadIdx.x;
  const int bid = blockIdx.x;
  const int mblk = bid & 255, nblk = bid >> 8;     // 256 x 24
  const int w = tid >> 6, l = tid & 63;
  const int wm = w >> 1, wn = w & 1;

  u16x8 pa[8], pb[8];
  #pragma unroll
  for (int i = 0; i < 8; ++i) {
    int e = tid + i * 256;
    int mt = e >> 8, kkl = (e >> 6) & 3, lane = e & 63;
    pa[i] = *((const u16x8*)g_x  + ((size_t)(mblk * 8 + mt) * 32 + kkl) * 64 + lane);
    pb[i] = *((const u16x8*)g_wih + ((size_t)(nblk * 8 + mt) * 32 + kkl) * 64 + lane);
  }
  f32x4 acc[4][4] = {};
  for (int c = 0; c < 8; ++c) {
    __syncthreads();
    #pragma unroll
    for (int i = 0; i < 8; ++i) {
      int e = tid + i * 256;
      ((u16x8*)As)[e] = pa[i];
      ((u16x8*)Bs)[e] = pb[i];
    }
    __syncthreads();
    if (c < 7) {
      #pragma unroll
      for (int i = 0; i < 8; ++i) {
        int e = tid + i * 256;
        int mt = e >> 8, kkl = (e >> 6) & 3, lane = e & 63;
        pa[i] = *((const u16x8*)g_x  + ((size_t)(mblk * 8 + mt) * 32 + (c + 1) * 4 + kkl) * 64 + lane);
        pb[i] = *((const u16x8*)g_wih + ((size_t)(nblk * 8 + mt) * 32 + (c + 1) * 4 + kkl) * 64 + lane);
      }
    }
    #pragma unroll
    for (int kkl = 0; kkl < 4; ++kkl) {
      bf16x8 af[4], bfr[4];
      #pragma unroll
      for (int ai = 0; ai < 4; ++ai) af[ai]  = ((const bf16x8*)As)[((wm * 4 + ai) * 4 + kkl) * 64 + l];
      #pragma unroll
      for (int bi = 0; bi < 4; ++bi) bfr[bi] = ((const bf16x8*)Bs)[((wn * 4 + bi) * 4 + kkl) * 64 + l];
      #pragma unroll
      for (int ai = 0; ai < 4; ++ai)
        #pragma unroll
        for (int bi = 0; bi < 4; ++bi)
          acc[ai][bi] = __builtin_amdgcn_mfma_f32_16x16x32_bf16(af[ai], bfr[bi], acc[ai][bi], 0, 0, 0);
    }
  }
  const int jj = l & 15;
  #pragma unroll
  for (int ai = 0; ai < 4; ++ai)
    #pragma unroll
    for (int bi = 0; bi < 4; ++bi) {
      int mt = mblk * 8 + wm * 4 + ai;       // = t*4+eg
      int nt = nblk * 8 + wn * 4 + bi;
      int gate = nt >> 6, jg = nt & 63;
      size_t base = ((size_t)mt * 64 + jg) * 768 + (size_t)gate * 256;
      #pragma unroll
      for (int i = 0; i < 4; ++i) {
        int env = (l >> 4) * 4 + i;
        g_gi[base + env * 16 + jj] = f2bf(acc[ai][bi][i]);
      }
    }
}

// ---- persistent scan: 256 wgs = (eg 0..3) x (jg 0..63), 1 wg/CU ----
__global__ __launch_bounds__(256) void scan_kernel(const float* __restrict__ hx,
                                                   const float* __restrict__ mask,
                                                   const float* __restrict__ bih,
                                                   const float* __restrict__ bhh,
                                                   float* __restrict__ out) {
  extern __shared__ char smem[];
  unsigned short* whhL = (unsigned short*)smem;          // 3 x 2048 vec8 = 96KB
  unsigned short* hA   = whhL + 3 * 2048 * 8;            // 32KB
  float* Cl = (float*)(hA + 2048 * 8);                   // 3KB

  const int tid = threadIdx.x;
  const int bid = blockIdx.x;
  const int eg = bid >> 6, jg = bid & 63;
  const int e0 = eg * 16;
  const int w3 = tid >> 6, l = tid & 63;
  const int e_ = tid >> 4, jj = tid & 15;
  const int j = jg * 16 + jj;

  // preload W_hh j-slice into LDS (gates r,z,n)
  #pragma unroll 4
  for (int i = 0; i < 24; ++i) {
    int e = tid + i * 256;                   // < 6144
    int gate = e >> 11, rem = e & 2047;
    ((u16x8*)whhL)[e] = *((const u16x8*)g_whh + (size_t)(gate * 64 + jg) * 2048 + rem);
  }

  // init h0 = hx * mask[0]; publish tile + flag=0
  const int lgrp = ((jg & 1) << 1) | (jj >> 3);
  const size_t widx = ((size_t)eg * 2048 + (jg >> 1) * 64 + (e_ | (lgrp << 4))) * 8 + (jj & 7);
  float hreg;
  {
    float h0 = hx[(size_t)(e0 + e_) * HH + j] * mask[e0 + e_];
    hreg = h0;
    store2_sc(g_hbuf + widx, f2bf(h0));      // parity 0
  }
  asm volatile("s_waitcnt vmcnt(0)" ::: "memory");
  __syncthreads();                           // also covers whhL writes
  if (tid == 0)
    __hip_atomic_store(&g_flags[eg * 64 + jg], 0, __ATOMIC_RELAXED, __HIP_MEMORY_SCOPE_AGENT);

  const float br  = bih[j] + bhh[j];
  const float bz  = bih[HH + j] + bhh[HH + j];
  const float bin = bih[2 * HH + j];
  const float bhn = bhh[2 * HH + j];

  for (int t = 0; t < TT; ++t) {
    // gi + next-mask loads issued early (latency hidden under poll)
    size_t gbase = ((size_t)(t * 4 + eg) * 64 + jg) * 768;
    float gr  = __uint_as_float((unsigned)g_gi[gbase + tid] << 16);
    float gz  = __uint_as_float((unsigned)g_gi[gbase + 256 + tid] << 16);
    float gn_ = __uint_as_float((unsigned)g_gi[gbase + 512 + tid] << 16);
    int tm = (t + 1 < TT) ? (t + 1) : (TT - 1);
    float mnext = mask[tm * NN + e0 + e_];

    // dataflow wait: all 64 jg tiles of this eg ready for step t
    while (true) {
      int v = __hip_atomic_load(&g_flags[eg * 64 + l], __ATOMIC_RELAXED, __HIP_MEMORY_SCOPE_AGENT);
      if (__all(v >= t)) break;
      __builtin_amdgcn_s_sleep(1);
    }
    asm volatile("" ::: "memory");

    // stage masked h tiles (LLC) -> LDS
    const u16x8* hsrc = (const u16x8*)g_hbuf + (size_t)((t & 1) * 4 + eg) * 2048;
    i32x4 hv[8];
    #pragma unroll
    for (int i = 0; i < 8; ++i) hv[i] = load16_sc(hsrc + tid + i * 256);
    asm volatile("s_waitcnt vmcnt(0)" ::: "memory");
    __builtin_amdgcn_sched_barrier(0);
    #pragma unroll
    for (int i = 0; i < 8; ++i) ((i32x4*)hA)[tid + i * 256] = hv[i];
    __syncthreads();

    // h-GEMM: wave w3 in {0,1,2} computes gate tile (r, z, h_n)
    if (w3 < 3) {
      const bf16x8* ap = (const bf16x8*)hA;
      const bf16x8* bp = (const bf16x8*)whhL + (size_t)w3 * 2048;
      f32x4 acc = {0.f, 0.f, 0.f, 0.f};
      #pragma unroll 8
      for (int kk = 0; kk < 32; ++kk)
        acc = __builtin_amdgcn_mfma_f32_16x16x32_bf16(ap[kk * 64 + l], bp[kk * 64 + l], acc, 0, 0, 0);
      int col = l & 15, r0 = (l >> 4) * 4;
      #pragma unroll
      for (int i = 0; i < 4; ++i) Cl[w3 * 256 + (r0 + i) * 16 + col] = acc[i];
    }
    __syncthreads();

    // elementwise GRU update (thread = (env e_, col jj))
    {
      float pr = gr + Cl[tid] + br;
      float pz = gz + Cl[256 + tid] + bz;
      float r = 1.f / (1.f + __expf(-pr));
      float z = 1.f / (1.f + __expf(-pz));
      float hn = Cl[512 + tid] + bhn;
      float gn = gn_ + bin + r * hn;
      float e2g = __expf(2.f * gn);
      float n = 1.f - 2.f / (e2g + 1.f);
      float hnew = (1.f - z) * n + z * hreg;
      out[(size_t)t * NN * HH + (size_t)(e0 + e_) * HH + j] = hnew;
      if (t == TT - 1)
        out[(size_t)TT * NN * HH + (size_t)(e0 + e_) * HH + j] = hnew;
      if (t + 1 < TT) {
        float hm = hnew * mnext;
        hreg = hm;
        store2_sc(g_hbuf + (size_t)((t + 1) & 1) * 4 * 2048 * 8 + widx, f2bf(hm));
      }
    }

    if (t + 1 < TT) {
      asm volatile("s_waitcnt vmcnt(0)" ::: "memory");
      __syncthreads();
      if (tid == 0)
        __hip_atomic_store(&g_flags[eg * 64 + jg], t + 1, __ATOMIC_RELAXED, __HIP_MEMORY_SCOPE_AGENT);
    }
  }
}

extern "C" void kernel_launch(void* const* d_in, const int* in_sizes, int n_in,
                              void* d_out, int out_size, void* d_ws, size_t ws_size,
                              hipStream_t stream) {
  (void)in_sizes; (void)n_in; (void)d_ws; (void)ws_size; (void)out_size;
  const float* x    = (const float*)d_in[0];
  const float* hx   = (const float*)d_in[1];
  const float* mask = (const float*)d_in[2];
  const float* wih  = (const float*)d_in[3];
  const float* whh  = (const float*)d_in[4];
  const float* bih  = (const float*)d_in[5];
  const float* bhh  = (const float*)d_in[6];
  float* out = (float*)d_out;

  hipFuncSetAttribute((const void*)gemm_gi, hipFuncAttributeMaxDynamicSharedMemorySize, 65536);
  hipFuncSetAttribute((const void*)scan_kernel, hipFuncAttributeMaxDynamicSharedMemorySize, 134144);

  prep_kernel<<<2048, 256, 0, stream>>>(x, wih, whh);
  gemm_gi<<<6144, 256, 65536, stream>>>();
  scan_kernel<<<256, 256, 134144, stream>>>(hx, mask, bih, bhh, out);
}

// Round 3
// 2304.394 us; speedup vs baseline: 4.3630x; 1.3492x over previous
//
#include <hip/hip_runtime.h>

#define TT 512
#define NN 64
#define DD 1024
#define HH 1024

typedef __attribute__((ext_vector_type(8))) short bf16x8;
typedef __attribute__((ext_vector_type(4))) float f32x4;
typedef __attribute__((ext_vector_type(8))) unsigned short u16x8;
typedef __attribute__((ext_vector_type(4))) int i32x4;

// ---- static device buffers (rewritten every launch by prep/gemm) ----
// fragment-tiled bf16: vec8 idx = (tile*32 + kk)*64 + lane, elem e:
//   matrix[col = tile*16 + (lane&15)][k = kk*32 + (lane>>4)*8 + e]
__device__ unsigned short g_wih[192u * 2048 * 8];            // 6 MB
__device__ unsigned short g_whh[192u * 2048 * 8];            // 6 MB
__device__ unsigned short g_x[2048u * 2048 * 8];             // 67 MB, tile=(t*4+eg)
// gi (x-projection, bf16): [(t*4+eg)*64 + jg][gate][env16][jj16]
__device__ unsigned short g_gi[(size_t)2048 * 64 * 768];     // 201 MB
// tagged h state: word = (tag<<16) | bf16(h); [parity][eg][16384 words]
__device__ unsigned g_hbuf32[2u * 4 * 16384];                // 512 KB

__device__ __forceinline__ unsigned short f2bf(float f) {
  unsigned u = __float_as_uint(f);
  u += 0x7fffu + ((u >> 16) & 1u);
  return (unsigned short)(u >> 16);
}

__global__ void prep_kernel(const float* __restrict__ x,
                            const float* __restrict__ wih,
                            const float* __restrict__ whh) {
  const int gsz = gridDim.x * blockDim.x;
  const int gid = blockIdx.x * blockDim.x + threadIdx.x;
  // zero the tag buffer (tag 0 = invalid; consuming tags are 1..512)
  for (int z = gid; z < 2 * 4 * 16384; z += gsz) g_hbuf32[z] = 0u;

  const int W8 = 192 * 2048;          // vec8 groups per weight matrix
  const int X8 = 2048 * 2048;         // vec8 groups for x
  for (int idx = gid; idx < 2 * W8 + X8; idx += gsz) {
    if (idx < 2 * W8) {
      const float* src = (idx < W8) ? wih : whh;
      unsigned short* dst = (idx < W8) ? g_wih : g_whh;
      int i8 = (idx < W8) ? idx : idx - W8;
      size_t g = (size_t)i8 * 8;
      int col = (int)(g >> 10);
      int k = (int)(g & 1023);
      int kk = k >> 5, lg = (k >> 3) & 3;
      int cg = col >> 4;
      int l = (col & 15) | (lg << 4);
      size_t o8 = ((size_t)cg * 32 + kk) * 64 + l;
      const float* p = src + g;
      float4 v0 = *(const float4*)(p);
      float4 v1 = *(const float4*)(p + 4);
      u16x8 u;
      u[0] = f2bf(v0.x); u[1] = f2bf(v0.y); u[2] = f2bf(v0.z); u[3] = f2bf(v0.w);
      u[4] = f2bf(v1.x); u[5] = f2bf(v1.y); u[6] = f2bf(v1.z); u[7] = f2bf(v1.w);
      *(u16x8*)(dst + o8 * 8) = u;
    } else {
      int i8 = idx - 2 * W8;
      size_t g = (size_t)i8 * 8;
      int row = (int)(g >> 10);             // t*64 + env
      int k = (int)(g & 1023);
      int t = row >> 6, env = row & 63;
      int eg = env >> 4;
      int kk = k >> 5, lg = (k >> 3) & 3;
      int l = (env & 15) | (lg << 4);
      size_t o8 = (((size_t)t * 4 + eg) * 32 + kk) * 64 + l;
      const float* p = x + g;
      float4 v0 = *(const float4*)(p);
      float4 v1 = *(const float4*)(p + 4);
      u16x8 u;
      u[0] = f2bf(v0.x); u[1] = f2bf(v0.y); u[2] = f2bf(v0.z); u[3] = f2bf(v0.w);
      u[4] = f2bf(v1.x); u[5] = f2bf(v1.y); u[6] = f2bf(v1.z); u[7] = f2bf(v1.w);
      *(u16x8*)(g_x + o8 * 8) = u;
    }
  }
}

// ---- gi = x * wih^T, 128x128 tile, BK=128, reg-prefetch + LDS ----
__global__ __launch_bounds__(256) void gemm_gi() {
  extern __shared__ char smem[];
  unsigned short* As = (unsigned short*)smem;      // 32KB
  unsigned short* Bs = As + 2048 * 8;              // 32KB
  const int tid = threadIdx.x;
  const int bid = blockIdx.x;
  const int mblk = bid & 255, nblk = bid >> 8;     // 256 x 24
  const int w = tid >> 6, l = tid & 63;
  const int wm = w >> 1, wn = w & 1;

  u16x8 pa[8], pb[8];
  #pragma unroll
  for (int i = 0; i < 8; ++i) {
    int e = tid + i * 256;
    int mt = e >> 8, kkl = (e >> 6) & 3, lane = e & 63;
    pa[i] = *((const u16x8*)g_x  + ((size_t)(mblk * 8 + mt) * 32 + kkl) * 64 + lane);
    pb[i] = *((const u16x8*)g_wih + ((size_t)(nblk * 8 + mt) * 32 + kkl) * 64 + lane);
  }
  f32x4 acc[4][4] = {};
  for (int c = 0; c < 8; ++c) {
    __syncthreads();
    #pragma unroll
    for (int i = 0; i < 8; ++i) {
      int e = tid + i * 256;
      ((u16x8*)As)[e] = pa[i];
      ((u16x8*)Bs)[e] = pb[i];
    }
    __syncthreads();
    if (c < 7) {
      #pragma unroll
      for (int i = 0; i < 8; ++i) {
        int e = tid + i * 256;
        int mt = e >> 8, kkl = (e >> 6) & 3, lane = e & 63;
        pa[i] = *((const u16x8*)g_x  + ((size_t)(mblk * 8 + mt) * 32 + (c + 1) * 4 + kkl) * 64 + lane);
        pb[i] = *((const u16x8*)g_wih + ((size_t)(nblk * 8 + mt) * 32 + (c + 1) * 4 + kkl) * 64 + lane);
      }
    }
    #pragma unroll
    for (int kkl = 0; kkl < 4; ++kkl) {
      bf16x8 af[4], bfr[4];
      #pragma unroll
      for (int ai = 0; ai < 4; ++ai) af[ai]  = ((const bf16x8*)As)[((wm * 4 + ai) * 4 + kkl) * 64 + l];
      #pragma unroll
      for (int bi = 0; bi < 4; ++bi) bfr[bi] = ((const bf16x8*)Bs)[((wn * 4 + bi) * 4 + kkl) * 64 + l];
      #pragma unroll
      for (int ai = 0; ai < 4; ++ai)
        #pragma unroll
        for (int bi = 0; bi < 4; ++bi)
          acc[ai][bi] = __builtin_amdgcn_mfma_f32_16x16x32_bf16(af[ai], bfr[bi], acc[ai][bi], 0, 0, 0);
    }
  }
  const int jj = l & 15;
  #pragma unroll
  for (int ai = 0; ai < 4; ++ai)
    #pragma unroll
    for (int bi = 0; bi < 4; ++bi) {
      int mt = mblk * 8 + wm * 4 + ai;       // = t*4+eg
      int nt = nblk * 8 + wn * 4 + bi;
      int gate = nt >> 6, jg = nt & 63;
      size_t base = ((size_t)mt * 64 + jg) * 768 + (size_t)gate * 256;
      #pragma unroll
      for (int i = 0; i < 4; ++i) {
        int env = (l >> 4) * 4 + i;
        g_gi[base + env * 16 + jj] = f2bf(acc[ai][bi][i]);
      }
    }
}

// ---- persistent scan: 256 wgs = (eg 0..3) x (jg 0..63), 1 wg/CU ----
__global__ __launch_bounds__(256) void scan_kernel(const float* __restrict__ hx,
                                                   const float* __restrict__ mask,
                                                   const float* __restrict__ bih,
                                                   const float* __restrict__ bhh,
                                                   float* __restrict__ out) {
  extern __shared__ char smem[];
  unsigned short* whhL = (unsigned short*)smem;          // 96KB
  unsigned short* hA   = whhL + 3 * 2048 * 8;            // 32KB
  float* Cl = (float*)(hA + 2048 * 8);                   // 3KB

  const int tid = threadIdx.x;
  const int bid = blockIdx.x;
  const int eg = bid >> 6, jg = bid & 63;
  const int e0 = eg * 16;
  const int w3 = tid >> 6, l = tid & 63;
  const int e_ = tid >> 4, jj = tid & 15;
  const int j = jg * 16 + jj;

  // preload W_hh j-slice into LDS (gates r,z,n)
  #pragma unroll 4
  for (int i = 0; i < 24; ++i) {
    int e = tid + i * 256;                   // < 6144
    int gate = e >> 11, rem = e & 2047;
    ((u16x8*)whhL)[e] = *((const u16x8*)g_whh + (size_t)(gate * 64 + jg) * 2048 + rem);
  }

  // producer word index for this thread's h[e0+e_][j]
  const int kf = jg * 16 + jj;
  const int widx = (((kf >> 5) * 64) + (e_ | (((kf >> 3) & 3) << 4))) * 8 + (kf & 7);

  // publish h0 = hx*mask[0] with tag 1 into parity-0 buffer
  float hreg;
  {
    float h0 = hx[(size_t)(e0 + e_) * HH + j] * mask[e0 + e_];
    hreg = h0;
    unsigned tw = (1u << 16) | (unsigned)f2bf(h0);
    unsigned* dst = g_hbuf32 + ((size_t)eg << 14) + widx;
    asm volatile("global_store_dword %0, %1, off sc0 sc1" :: "v"(dst), "v"(tw) : "memory");
  }

  const float br  = bih[j] + bhh[j];
  const float bz  = bih[HH + j] + bhh[HH + j];
  const float bin = bih[2 * HH + j];
  const float bhn = bhh[2 * HH + j];

  // gi prefetch for t=0
  unsigned short pgr, pgz, pgn;
  {
    size_t gb = ((size_t)eg * 64 + jg) * 768;
    pgr = g_gi[gb + tid]; pgz = g_gi[gb + 256 + tid]; pgn = g_gi[gb + 512 + tid];
  }

  const unsigned voff = (unsigned)tid * 32;

  for (int t = 0; t < TT; ++t) {
    int tm = (t + 1 < TT) ? (t + 1) : (TT - 1);
    float mnext = mask[tm * NN + e0 + e_];

    // ---- poll tagged h data (single LLC trip; retry while stale) ----
    const unsigned* hb = g_hbuf32 + (((size_t)(t & 1) * 4 + eg) << 14);
    const unsigned tagp = (unsigned)(t + 1) << 16;
    i32x4 hv[16];
    while (true) {
      #pragma unroll
      for (int i = 0; i < 8; ++i) {
        asm volatile("global_load_dwordx4 %0, %2, %3 sc0 sc1\n\t"
                     "global_load_dwordx4 %1, %2, %3 offset:16 sc0 sc1"
                     : "=&v"(hv[2 * i]), "=&v"(hv[2 * i + 1])
                     : "v"(voff), "s"(hb + i * 2048));
      }
      asm volatile("s_waitcnt vmcnt(0)" ::: "memory");
      __builtin_amdgcn_sched_barrier(0);
      unsigned bad = 0;
      #pragma unroll
      for (int i = 0; i < 16; ++i) {
        bad |= ((unsigned)hv[i][0] ^ tagp); bad |= ((unsigned)hv[i][1] ^ tagp);
        bad |= ((unsigned)hv[i][2] ^ tagp); bad |= ((unsigned)hv[i][3] ^ tagp);
      }
      bad &= 0xFFFF0000u;
      if (__all(bad == 0)) break;
      __builtin_amdgcn_s_sleep(1);
    }

    // ---- unpack tagged words -> bf16 pairs -> LDS ----
    #pragma unroll
    for (int i = 0; i < 8; ++i) {
      i32x4 a = hv[2 * i], b = hv[2 * i + 1];
      i32x4 pk;
      pk[0] = (int)__builtin_amdgcn_perm((unsigned)a[1], (unsigned)a[0], 0x05040100u);
      pk[1] = (int)__builtin_amdgcn_perm((unsigned)a[3], (unsigned)a[2], 0x05040100u);
      pk[2] = (int)__builtin_amdgcn_perm((unsigned)b[1], (unsigned)b[0], 0x05040100u);
      pk[3] = (int)__builtin_amdgcn_perm((unsigned)b[3], (unsigned)b[2], 0x05040100u);
      ((i32x4*)hA)[tid + i * 256] = pk;
    }
    __syncthreads();

    // consume prefetched gi, then prefetch next step's gi (latency-hidden)
    float gr  = __uint_as_float((unsigned)pgr << 16);
    float gz  = __uint_as_float((unsigned)pgz << 16);
    float gn_ = __uint_as_float((unsigned)pgn << 16);
    if (t + 1 < TT) {
      size_t gb = ((size_t)((t + 1) * 4 + eg) * 64 + jg) * 768;
      pgr = g_gi[gb + tid]; pgz = g_gi[gb + 256 + tid]; pgn = g_gi[gb + 512 + tid];
    }

    // ---- h-GEMM: wave w3 in {0,1,2} computes gate tile (r, z, h_n) ----
    if (w3 < 3) {
      const bf16x8* ap = (const bf16x8*)hA;
      const bf16x8* bp = (const bf16x8*)whhL + (size_t)w3 * 2048;
      f32x4 acc0 = {0.f, 0.f, 0.f, 0.f}, acc1 = {0.f, 0.f, 0.f, 0.f};
      #pragma unroll 8
      for (int kk = 0; kk < 16; ++kk) {
        acc0 = __builtin_amdgcn_mfma_f32_16x16x32_bf16(ap[kk * 64 + l], bp[kk * 64 + l], acc0, 0, 0, 0);
        acc1 = __builtin_amdgcn_mfma_f32_16x16x32_bf16(ap[(kk + 16) * 64 + l], bp[(kk + 16) * 64 + l], acc1, 0, 0, 0);
      }
      int col = l & 15, r0 = (l >> 4) * 4;
      #pragma unroll
      for (int i = 0; i < 4; ++i) Cl[w3 * 256 + (r0 + i) * 16 + col] = acc0[i] + acc1[i];
    }
    __syncthreads();

    // ---- elementwise GRU update (thread = (env e_, col jj)) ----
    {
      float pr = gr + Cl[tid] + br;
      float pz = gz + Cl[256 + tid] + bz;
      float r = 1.f / (1.f + __expf(-pr));
      float z = 1.f / (1.f + __expf(-pz));
      float hn = Cl[512 + tid] + bhn;
      float gn = gn_ + bin + r * hn;
      float e2g = __expf(2.f * gn);
      float n = 1.f - 2.f / (e2g + 1.f);
      float hnew = (1.f - z) * n + z * hreg;
      if (t + 1 < TT) {
        float hm = hnew * mnext;
        hreg = hm;
        unsigned tw = ((unsigned)(t + 2) << 16) | (unsigned)f2bf(hm);
        unsigned* dst = g_hbuf32 + (((size_t)((t + 1) & 1) * 4 + eg) << 14) + widx;
        asm volatile("global_store_dword %0, %1, off sc0 sc1" :: "v"(dst), "v"(tw) : "memory");
      }
      out[(size_t)t * NN * HH + (size_t)(e0 + e_) * HH + j] = hnew;
      if (t == TT - 1)
        out[(size_t)TT * NN * HH + (size_t)(e0 + e_) * HH + j] = hnew;
    }
  }
}

extern "C" void kernel_launch(void* const* d_in, const int* in_sizes, int n_in,
                              void* d_out, int out_size, void* d_ws, size_t ws_size,
                              hipStream_t stream) {
  (void)in_sizes; (void)n_in; (void)d_ws; (void)ws_size; (void)out_size;
  const float* x    = (const float*)d_in[0];
  const float* hx   = (const float*)d_in[1];
  const float* mask = (const float*)d_in[2];
  const float* wih  = (const float*)d_in[3];
  const float* whh  = (const float*)d_in[4];
  const float* bih  = (const float*)d_in[5];
  const float* bhh  = (const float*)d_in[6];
  float* out = (float*)d_out;

  hipFuncSetAttribute((const void*)gemm_gi, hipFuncAttributeMaxDynamicSharedMemorySize, 65536);
  hipFuncSetAttribute((const void*)scan_kernel, hipFuncAttributeMaxDynamicSharedMemorySize, 134144);

  prep_kernel<<<2048, 256, 0, stream>>>(x, wih, whh);
  gemm_gi<<<6144, 256, 65536, stream>>>();
  scan_kernel<<<256, 256, 134144, stream>>>(hx, mask, bih, bhh, out);
}